// Round 1
// baseline (553.372 us; speedup 1.0000x reference)
//
#include <hip/hip_runtime.h>
#include <hip/hip_bf16.h>

// ScalarQLinear: out = x @ w_q^T + bias, w_q = clip(rint(w/||row||*60), -8, 7) * ||row||/60
// Strategy: scale factors commute out of the GEMM; q in [-8,7] is exact in bf16.
//   K1: per-row quantize w -> bf16 q + fp32 scale (ws)
//   K2: x fp32 -> bf16 (ws)
//   K3: bf16 MFMA GEMM (m97 structure: 128x128 tile, BK=32, global_load_lds w=16),
//       epilogue applies scale[n] and bias[n].

typedef __bf16 bf16x8 __attribute__((ext_vector_type(8)));
typedef __bf16 bf16x4 __attribute__((ext_vector_type(4)));
typedef float floatx4 __attribute__((ext_vector_type(4)));

#define MDIM 8192
#define NDIM 4096
#define KDIM 4096

__device__ __forceinline__ void async_copy16(const void* g, void* l) {
  __builtin_amdgcn_global_load_lds(
      (const __attribute__((address_space(1))) void*)g,
      (__attribute__((address_space(3))) void*)l, 16, 0, 0);
}

// --- K1: quantize weight rows. One block (256 thr) per row of 4096 fp32. ---
__global__ __launch_bounds__(256) void quantize_w(const float* __restrict__ w,
                                                  __bf16* __restrict__ qb,
                                                  float* __restrict__ scale) {
  const int row = blockIdx.x;
  const int t = threadIdx.x;
  const float4* wr = (const float4*)(w + (size_t)row * KDIM);
  float4 v[4];
  float ss = 0.f;
#pragma unroll
  for (int i = 0; i < 4; ++i) {
    v[i] = wr[t + 256 * i];
    ss += v[i].x * v[i].x + v[i].y * v[i].y + v[i].z * v[i].z + v[i].w * v[i].w;
  }
#pragma unroll
  for (int m = 32; m >= 1; m >>= 1) ss += __shfl_xor(ss, m, 64);
  __shared__ float wsum[4];
  if ((t & 63) == 0) wsum[t >> 6] = ss;
  __syncthreads();
  const float tot = wsum[0] + wsum[1] + wsum[2] + wsum[3];
  const float safe = fmaxf(sqrtf(tot), 1e-8f);

  bf16x4* qr = (bf16x4*)(qb + (size_t)row * KDIM);
#pragma unroll
  for (int i = 0; i < 4; ++i) {
    // match reference order: (w / norm_safe) * 60, rint = round-half-even
    float q0 = fminf(fmaxf(rintf(v[i].x / safe * 60.0f), -8.f), 7.f);
    float q1 = fminf(fmaxf(rintf(v[i].y / safe * 60.0f), -8.f), 7.f);
    float q2 = fminf(fmaxf(rintf(v[i].z / safe * 60.0f), -8.f), 7.f);
    float q3 = fminf(fmaxf(rintf(v[i].w / safe * 60.0f), -8.f), 7.f);
    bf16x4 o = {(__bf16)q0, (__bf16)q1, (__bf16)q2, (__bf16)q3};  // exact
    qr[t + 256 * i] = o;
  }
  if (t == 0) scale[row] = safe / 60.0f;
}

// --- K2: x fp32 -> bf16 ---
__global__ __launch_bounds__(256) void convert_x(const float4* __restrict__ x,
                                                 bf16x4* __restrict__ xb) {
  const int n4 = (MDIM * KDIM) / 4;  // 8388608
  const int stride = gridDim.x * 256;
  for (int idx = blockIdx.x * 256 + threadIdx.x; idx < n4; idx += stride) {
    float4 v = x[idx];
    bf16x4 o = {(__bf16)v.x, (__bf16)v.y, (__bf16)v.z, (__bf16)v.w};
    xb[idx] = o;
  }
}

// --- K3: C[m,n] = scale[n] * sum_k A[m,k]*B[n,k] + bias[n] (A,B bf16; C fp32) ---
__global__ __launch_bounds__(256) void gemm_bt(const __bf16* __restrict__ A,
                                               const __bf16* __restrict__ B,
                                               const float* __restrict__ scale,
                                               const float* __restrict__ bias,
                                               float* __restrict__ C) {
  __shared__ __align__(16) __bf16 sA[128 * 32];
  __shared__ __align__(16) __bf16 sB[128 * 32];
  const int tid = threadIdx.x;
  const int m0 = blockIdx.y * 128;
  const int n0 = blockIdx.x * 128;

  // staging: flat tile layout [row][32 bf16], 16 B per lane, 2 chunks per operand
  const int srow = tid >> 2;            // 0..63
  const int scol = (tid & 3) * 16;      // byte offset within 64 B row
  const char* gA0 = (const char*)(A + (size_t)(m0 + srow) * KDIM) + scol;
  const char* gA1 = gA0 + (size_t)64 * KDIM * sizeof(__bf16);
  const char* gB0 = (const char*)(B + (size_t)(n0 + srow) * KDIM) + scol;
  const char* gB1 = gB0 + (size_t)64 * KDIM * sizeof(__bf16);
  char* lA0 = (char*)sA + tid * 16;   // wave-uniform base + lane*16 (required)
  char* lA1 = lA0 + 4096;
  char* lB0 = (char*)sB + tid * 16;
  char* lB1 = lB0 + 4096;

  const int lane = tid & 63;
  const int wid = tid >> 6;
  const int wm = (wid & 1) * 64;
  const int wn = (wid >> 1) * 64;
  const int fr = lane & 15;        // A: m, B: n, C/D: col
  const int fk = (lane >> 4) * 8;  // k offset within BK=32

  floatx4 acc[4][4] = {};

  for (int kt = 0; kt < KDIM / 32; ++kt) {
    __syncthreads();  // prior-iter LDS reads done before overwrite
    async_copy16(gA0, lA0);
    async_copy16(gA1, lA1);
    async_copy16(gB0, lB0);
    async_copy16(gB1, lB1);
    __syncthreads();  // compiler emits vmcnt(0) drain before s_barrier
    gA0 += 64; gA1 += 64; gB0 += 64; gB1 += 64;

    bf16x8 af[4], bg[4];
#pragma unroll
    for (int i = 0; i < 4; ++i)
      af[i] = *(const bf16x8*)&sA[(wm + i * 16 + fr) * 32 + fk];
#pragma unroll
    for (int j = 0; j < 4; ++j)
      bg[j] = *(const bf16x8*)&sB[(wn + j * 16 + fr) * 32 + fk];
#pragma unroll
    for (int i = 0; i < 4; ++i)
#pragma unroll
      for (int j = 0; j < 4; ++j)
        acc[i][j] = __builtin_amdgcn_mfma_f32_16x16x32_bf16(af[i], bg[j], acc[i][j], 0, 0, 0);
  }

  // epilogue: C/D layout col = lane&15, row = (lane>>4)*4 + reg (m89-verified)
  float scl[4], bs[4];
#pragma unroll
  for (int j = 0; j < 4; ++j) {
    const int n = n0 + wn + j * 16 + fr;
    scl[j] = scale[n];
    bs[j] = bias[n];
  }
  const int mrow = (lane >> 4) * 4;
#pragma unroll
  for (int i = 0; i < 4; ++i) {
#pragma unroll
    for (int r = 0; r < 4; ++r) {
      const size_t m = (size_t)(m0 + wm + i * 16 + mrow + r);
      float* crow = C + m * NDIM + (n0 + wn + fr);
#pragma unroll
      for (int j = 0; j < 4; ++j)
        crow[j * 16] = acc[i][j][r] * scl[j] + bs[j];
    }
  }
}

extern "C" void kernel_launch(void* const* d_in, const int* in_sizes, int n_in,
                              void* d_out, int out_size, void* d_ws, size_t ws_size,
                              hipStream_t stream) {
  (void)in_sizes; (void)n_in; (void)out_size; (void)ws_size;
  const float* x = (const float*)d_in[0];     // [8192, 4096]
  const float* w = (const float*)d_in[1];     // [4096, 4096]
  const float* bias = (const float*)d_in[2];  // [4096]
  float* out = (float*)d_out;                 // [8192, 4096]

  char* ws = (char*)d_ws;
  __bf16* xb = (__bf16*)ws;                                    // 64 MB
  __bf16* qb = (__bf16*)(ws + (size_t)67108864);               // 32 MB
  float* scale = (float*)(ws + (size_t)67108864 + 33554432);   // 16 KB

  quantize_w<<<NDIM, 256, 0, stream>>>(w, qb, scale);
  convert_x<<<8192, 256, 0, stream>>>((const float4*)x, (bf16x4*)xb);
  dim3 grid(NDIM / 128, MDIM / 128);  // (32, 64)
  gemm_bt<<<grid, 256, 0, stream>>>(xb, qb, scale, bias, out);
}

// Round 2
// 414.053 us; speedup vs baseline: 1.3365x; 1.3365x over previous
//
#include <hip/hip_runtime.h>
#include <hip/hip_bf16.h>

// ScalarQLinear via int8 MFMA:
//   q_w in [-8,7] is EXACT in int8; x quantized per-row to int8 (absmax/127).
//   out[m,n] = sx[m]*scale[n] * (qx[m,:] . qw[n,:]) + bias[n], i32 accum exact.
//   GEMM: m97 skeleton, 128x128 tile, BK=64 (64 B/row, same staging shape as
//   bf16 BK=32), mfma_i32_16x16x64_i8 (2x bf16 rate), half the K-trips.

typedef int int32x4 __attribute__((ext_vector_type(4)));

#define MDIM 8192
#define NDIM 4096
#define KDIM 4096

__device__ __forceinline__ void async_copy16(const void* g, void* l) {
  __builtin_amdgcn_global_load_lds(
      (const __attribute__((address_space(1))) void*)g,
      (__attribute__((address_space(3))) void*)l, 16, 0, 0);
}

__device__ __forceinline__ unsigned pack4(float a, float b, float c, float d) {
  return ((unsigned)((int)a & 0xff)) | ((unsigned)((int)b & 0xff) << 8) |
         ((unsigned)((int)c & 0xff) << 16) | ((unsigned)((int)d & 0xff) << 24);
}

// --- K1: quantize weight rows -> int8 q + fp32 scale. One block per row. ---
__global__ __launch_bounds__(256) void quantize_w(const float* __restrict__ w,
                                                  unsigned* __restrict__ qw,
                                                  float* __restrict__ scale) {
  const int row = blockIdx.x;
  const int t = threadIdx.x;
  const float4* wr = (const float4*)(w + (size_t)row * KDIM);
  float4 v[4];
  float ss = 0.f;
#pragma unroll
  for (int i = 0; i < 4; ++i) {
    v[i] = wr[t + 256 * i];
    ss += v[i].x * v[i].x + v[i].y * v[i].y + v[i].z * v[i].z + v[i].w * v[i].w;
  }
#pragma unroll
  for (int m = 32; m >= 1; m >>= 1) ss += __shfl_xor(ss, m, 64);
  __shared__ float wsum[4];
  if ((t & 63) == 0) wsum[t >> 6] = ss;
  __syncthreads();
  const float safe = fmaxf(sqrtf(wsum[0] + wsum[1] + wsum[2] + wsum[3]), 1e-8f);

  unsigned* qr = qw + (size_t)row * (KDIM / 4);
#pragma unroll
  for (int i = 0; i < 4; ++i) {
    // keep reference op order: (w / norm) * 60, round-half-even, clip [-8,7]
    float q0 = fminf(fmaxf(rintf(v[i].x / safe * 60.0f), -8.f), 7.f);
    float q1 = fminf(fmaxf(rintf(v[i].y / safe * 60.0f), -8.f), 7.f);
    float q2 = fminf(fmaxf(rintf(v[i].z / safe * 60.0f), -8.f), 7.f);
    float q3 = fminf(fmaxf(rintf(v[i].w / safe * 60.0f), -8.f), 7.f);
    qr[t + 256 * i] = pack4(q0, q1, q2, q3);
  }
  if (t == 0) scale[row] = safe / 60.0f;
}

// --- K2: quantize x rows -> int8 (per-row absmax/127) + fp32 sx. ---
__global__ __launch_bounds__(256) void quantize_x(const float* __restrict__ x,
                                                  unsigned* __restrict__ qx,
                                                  float* __restrict__ sx) {
  const int row = blockIdx.x;
  const int t = threadIdx.x;
  const float4* xr = (const float4*)(x + (size_t)row * KDIM);
  float4 v[4];
  float am = 0.f;
#pragma unroll
  for (int i = 0; i < 4; ++i) {
    v[i] = xr[t + 256 * i];
    am = fmaxf(am, fmaxf(fmaxf(fabsf(v[i].x), fabsf(v[i].y)),
                         fmaxf(fabsf(v[i].z), fabsf(v[i].w))));
  }
#pragma unroll
  for (int m = 32; m >= 1; m >>= 1) am = fmaxf(am, __shfl_xor(am, m, 64));
  __shared__ float wmax[4];
  if ((t & 63) == 0) wmax[t >> 6] = am;
  __syncthreads();
  const float amax = fmaxf(fmaxf(fmaxf(wmax[0], wmax[1]), fmaxf(wmax[2], wmax[3])), 1e-20f);
  const float r = 127.0f / amax;

  unsigned* qr = qx + (size_t)row * (KDIM / 4);
#pragma unroll
  for (int i = 0; i < 4; ++i) {
    float q0 = fminf(fmaxf(rintf(v[i].x * r), -127.f), 127.f);
    float q1 = fminf(fmaxf(rintf(v[i].y * r), -127.f), 127.f);
    float q2 = fminf(fmaxf(rintf(v[i].z * r), -127.f), 127.f);
    float q3 = fminf(fmaxf(rintf(v[i].w * r), -127.f), 127.f);
    qr[t + 256 * i] = pack4(q0, q1, q2, q3);
  }
  if (t == 0) sx[row] = amax / 127.0f;
}

// --- K3: C[m,n] = sx[m]*scale[n]*dot_i8(A[m,:],B[n,:]) + bias[n] ---
__global__ __launch_bounds__(256) void gemm_i8(const char* __restrict__ A,
                                               const char* __restrict__ B,
                                               const float* __restrict__ sx,
                                               const float* __restrict__ scale,
                                               const float* __restrict__ bias,
                                               float* __restrict__ C) {
  __shared__ __align__(16) char sA[128 * 64];  // 8 KB: 128 rows x 64 i8 (BK=64)
  __shared__ __align__(16) char sB[128 * 64];  // 8 KB
  const int tid = threadIdx.x;
  const int m0 = blockIdx.y * 128;
  const int n0 = blockIdx.x * 128;

  // staging: 16 B/lane, flat lane-order LDS (global_load_lds constraint)
  const int srow = tid >> 2;        // 0..63
  const int scol = (tid & 3) * 16;  // byte offset in 64 B row
  const char* gA0 = A + (size_t)(m0 + srow) * KDIM + scol;
  const char* gA1 = gA0 + (size_t)64 * KDIM;
  const char* gB0 = B + (size_t)(n0 + srow) * KDIM + scol;
  const char* gB1 = gB0 + (size_t)64 * KDIM;
  char* lA0 = sA + tid * 16;
  char* lA1 = lA0 + 4096;
  char* lB0 = sB + tid * 16;
  char* lB1 = lB0 + 4096;

  const int lane = tid & 63;
  const int wid = tid >> 6;
  const int wm = (wid & 1) * 64;
  const int wn = (wid >> 1) * 64;
  const int fr = lane & 15;          // A: m, B: n
  const int fk = (lane >> 4) * 16;   // k byte offset within BK=64 (16 i8/lane)

  int32x4 acc[4][4] = {};

  for (int kt = 0; kt < KDIM / 64; ++kt) {  // 64 iterations
    __syncthreads();
    async_copy16(gA0, lA0);
    async_copy16(gA1, lA1);
    async_copy16(gB0, lB0);
    async_copy16(gB1, lB1);
    __syncthreads();
    gA0 += 64; gA1 += 64; gB0 += 64; gB1 += 64;

    int32x4 af[4], bg[4];
#pragma unroll
    for (int i = 0; i < 4; ++i)
      af[i] = *(const int32x4*)&sA[(wm + i * 16 + fr) * 64 + fk];
#pragma unroll
    for (int j = 0; j < 4; ++j)
      bg[j] = *(const int32x4*)&sB[(wn + j * 16 + fr) * 64 + fk];
#pragma unroll
    for (int i = 0; i < 4; ++i)
#pragma unroll
      for (int j = 0; j < 4; ++j)
        acc[i][j] = __builtin_amdgcn_mfma_i32_16x16x64_i8(af[i], bg[j], acc[i][j], 0, 0, 0);
  }

  // epilogue: C/D layout col = lane&15, row = quad*4 + reg (shape-determined)
  float scl[4], bs[4];
#pragma unroll
  for (int j = 0; j < 4; ++j) {
    const int n = n0 + wn + j * 16 + fr;
    scl[j] = scale[n];
    bs[j] = bias[n];
  }
  const int mrow = (lane >> 4) * 4;
#pragma unroll
  for (int i = 0; i < 4; ++i) {
#pragma unroll
    for (int r = 0; r < 4; ++r) {
      const size_t m = (size_t)(m0 + wm + i * 16 + mrow + r);
      const float sxm = sx[m];
      float* crow = C + m * NDIM + (n0 + wn + fr);
#pragma unroll
      for (int j = 0; j < 4; ++j)
        crow[j * 16] = (float)acc[i][j][r] * (sxm * scl[j]) + bs[j];
    }
  }
}

extern "C" void kernel_launch(void* const* d_in, const int* in_sizes, int n_in,
                              void* d_out, int out_size, void* d_ws, size_t ws_size,
                              hipStream_t stream) {
  (void)in_sizes; (void)n_in; (void)out_size; (void)ws_size;
  const float* x = (const float*)d_in[0];     // [8192, 4096] fp32
  const float* w = (const float*)d_in[1];     // [4096, 4096] fp32
  const float* bias = (const float*)d_in[2];  // [4096] fp32
  float* out = (float*)d_out;                 // [8192, 4096] fp32

  char* ws = (char*)d_ws;
  char* qx = ws;                                   // 32 MB int8
  char* qw = ws + (size_t)33554432;                // 16 MB int8
  float* sx = (float*)(ws + (size_t)50331648);     // 32 KB
  float* scale = (float*)(ws + (size_t)50331648 + 65536);  // 16 KB

  quantize_w<<<NDIM, 256, 0, stream>>>(w, (unsigned*)qw, scale);
  quantize_x<<<MDIM, 256, 0, stream>>>(x, (unsigned*)qx, sx);
  dim3 grid(NDIM / 128, MDIM / 128);  // (32, 64)
  gemm_i8<<<grid, 256, 0, stream>>>(qx, qw, sx, scale, bias, out);
}

// Round 3
// 395.929 us; speedup vs baseline: 1.3977x; 1.0458x over previous
//
#include <hip/hip_runtime.h>
#include <hip/hip_bf16.h>

// ScalarQLinear via int8 MFMA, round 3:
//   - BK=128 (32 KB LDS): halves barrier/drain count per unit MFMA work.
//     32 K-iters, 8 global_load_lds + 32 mfma_i32_16x16x64_i8 per iter.
//   - XOR chunk swizzle (phys16B = logical16B ^ (row&7)): kills the 16-way
//     bank conflict a 128B-row-stride flat layout would have (2-way = free).
//     Staging picks the permuted global chunk so LDS lands pre-swizzled
//     (global_load_lds requires flat lane-order LDS placement; we permute
//     the SOURCE instead).
//   - Quantizers fused into one launch.

typedef int int32x4 __attribute__((ext_vector_type(4)));

#define MDIM 8192
#define NDIM 4096
#define KDIM 4096

__device__ __forceinline__ void async_copy16(const void* g, void* l) {
  __builtin_amdgcn_global_load_lds(
      (const __attribute__((address_space(1))) void*)g,
      (__attribute__((address_space(3))) void*)l, 16, 0, 0);
}

__device__ __forceinline__ unsigned pack4(float a, float b, float c, float d) {
  return ((unsigned)((int)a & 0xff)) | ((unsigned)((int)b & 0xff) << 8) |
         ((unsigned)((int)c & 0xff) << 16) | ((unsigned)((int)d & 0xff) << 24);
}

// --- K1: fused quantizers. Blocks [0,4096): w rows; [4096,12288): x rows. ---
__global__ __launch_bounds__(256) void quantize_all(
    const float* __restrict__ w, const float* __restrict__ x,
    unsigned* __restrict__ qw, unsigned* __restrict__ qx,
    float* __restrict__ scale, float* __restrict__ sx) {
  const int t = threadIdx.x;
  __shared__ float wred[4];
  if (blockIdx.x < NDIM) {
    const int row = blockIdx.x;
    const float4* wr = (const float4*)(w + (size_t)row * KDIM);
    float4 v[4];
    float ss = 0.f;
#pragma unroll
    for (int i = 0; i < 4; ++i) {
      v[i] = wr[t + 256 * i];
      ss += v[i].x * v[i].x + v[i].y * v[i].y + v[i].z * v[i].z + v[i].w * v[i].w;
    }
#pragma unroll
    for (int m = 32; m >= 1; m >>= 1) ss += __shfl_xor(ss, m, 64);
    if ((t & 63) == 0) wred[t >> 6] = ss;
    __syncthreads();
    const float safe = fmaxf(sqrtf(wred[0] + wred[1] + wred[2] + wred[3]), 1e-8f);
    unsigned* qr = qw + (size_t)row * (KDIM / 4);
#pragma unroll
    for (int i = 0; i < 4; ++i) {
      float q0 = fminf(fmaxf(rintf(v[i].x / safe * 60.0f), -8.f), 7.f);
      float q1 = fminf(fmaxf(rintf(v[i].y / safe * 60.0f), -8.f), 7.f);
      float q2 = fminf(fmaxf(rintf(v[i].z / safe * 60.0f), -8.f), 7.f);
      float q3 = fminf(fmaxf(rintf(v[i].w / safe * 60.0f), -8.f), 7.f);
      qr[t + 256 * i] = pack4(q0, q1, q2, q3);
    }
    if (t == 0) scale[row] = safe / 60.0f;
  } else {
    const int row = blockIdx.x - NDIM;
    const float4* xr = (const float4*)(x + (size_t)row * KDIM);
    float4 v[4];
    float am = 0.f;
#pragma unroll
    for (int i = 0; i < 4; ++i) {
      v[i] = xr[t + 256 * i];
      am = fmaxf(am, fmaxf(fmaxf(fabsf(v[i].x), fabsf(v[i].y)),
                           fmaxf(fabsf(v[i].z), fabsf(v[i].w))));
    }
#pragma unroll
    for (int m = 32; m >= 1; m >>= 1) am = fmaxf(am, __shfl_xor(am, m, 64));
    if ((t & 63) == 0) wred[t >> 6] = am;
    __syncthreads();
    const float amax =
        fmaxf(fmaxf(fmaxf(wred[0], wred[1]), fmaxf(wred[2], wred[3])), 1e-20f);
    const float r = 127.0f / amax;
    unsigned* qr = qx + (size_t)row * (KDIM / 4);
#pragma unroll
    for (int i = 0; i < 4; ++i) {
      float q0 = fminf(fmaxf(rintf(v[i].x * r), -127.f), 127.f);
      float q1 = fminf(fmaxf(rintf(v[i].y * r), -127.f), 127.f);
      float q2 = fminf(fmaxf(rintf(v[i].z * r), -127.f), 127.f);
      float q3 = fminf(fmaxf(rintf(v[i].w * r), -127.f), 127.f);
      qr[t + 256 * i] = pack4(q0, q1, q2, q3);
    }
    if (t == 0) sx[row] = amax / 127.0f;
  }
}

// --- K2: C[m,n] = sx[m]*scale[n]*dot_i8(A[m,:],B[n,:]) + bias[n] ---
// 128x128 tile, BK=128, swizzled LDS chunks.
__global__ __launch_bounds__(256) void gemm_i8(const char* __restrict__ A,
                                               const char* __restrict__ B,
                                               const float* __restrict__ sx,
                                               const float* __restrict__ scale,
                                               const float* __restrict__ bias,
                                               float* __restrict__ C) {
  __shared__ __align__(16) char sA[128 * 128];  // 16 KB
  __shared__ __align__(16) char sB[128 * 128];  // 16 KB
  const int tid = threadIdx.x;
  const int m0 = blockIdx.y * 128;
  const int n0 = blockIdx.x * 128;

  // staging: lane tid writes LDS at issue*4096 + tid*16 (flat, HW-required).
  // That slot is (row = issue*32 + (tid>>3), phys_chunk = tid&7).
  // phys = logical ^ (row&7)  =>  fetch global chunk (tid&7) ^ ((tid>>3)&7).
  const int r0 = tid >> 3;                               // 0..31
  const int c16 = ((tid & 7) ^ ((tid >> 3) & 7)) * 16;   // swizzled source col
  const char* gA = A + (size_t)(m0 + r0) * KDIM + c16;
  const char* gB = B + (size_t)(n0 + r0) * KDIM + c16;
  char* lA = sA + tid * 16;
  char* lB = sB + tid * 16;

  const int lane = tid & 63;
  const int wid = tid >> 6;
  const int wm = (wid & 1) * 64;
  const int wn = (wid >> 1) * 64;
  const int fr = lane & 15;   // A: m, B: n
  const int q = lane >> 4;    // k-quad within the 64-wide MFMA K
  const int sw = fr & 7;
  // physical 16B-chunk byte offsets for k-halves h=0,1: ((h*4+q)^sw)*16
  const int ph0 = ((q) ^ sw) * 16;
  const int ph1 = ((4 + q) ^ sw) * 16;

  int32x4 acc[4][4] = {};

  for (int kt = 0; kt < KDIM / 128; ++kt) {  // 32 iterations
    __syncthreads();
#pragma unroll
    for (int i = 0; i < 4; ++i) {
      async_copy16(gA + (size_t)(32 * i) * KDIM, lA + i * 4096);
      async_copy16(gB + (size_t)(32 * i) * KDIM, lB + i * 4096);
    }
    __syncthreads();
    gA += 128; gB += 128;

#pragma unroll
    for (int h = 0; h < 2; ++h) {
      const int ph = h ? ph1 : ph0;
      int32x4 af[4], bg[4];
#pragma unroll
      for (int i = 0; i < 4; ++i)
        af[i] = *(const int32x4*)&sA[(wm + i * 16 + fr) * 128 + ph];
#pragma unroll
      for (int j = 0; j < 4; ++j)
        bg[j] = *(const int32x4*)&sB[(wn + j * 16 + fr) * 128 + ph];
#pragma unroll
      for (int i = 0; i < 4; ++i)
#pragma unroll
        for (int j = 0; j < 4; ++j)
          acc[i][j] =
              __builtin_amdgcn_mfma_i32_16x16x64_i8(af[i], bg[j], acc[i][j], 0, 0, 0);
    }
  }

  // epilogue: C/D layout col = lane&15, row = quad*4 + reg (shape-determined)
  float scl[4], bs[4];
#pragma unroll
  for (int j = 0; j < 4; ++j) {
    const int n = n0 + wn + j * 16 + fr;
    scl[j] = scale[n];
    bs[j] = bias[n];
  }
  const int mrow = q * 4;
#pragma unroll
  for (int i = 0; i < 4; ++i) {
#pragma unroll
    for (int r = 0; r < 4; ++r) {
      const size_t m = (size_t)(m0 + wm + i * 16 + mrow + r);
      const float sxm = sx[m];
      float* crow = C + m * NDIM + (n0 + wn + fr);
#pragma unroll
      for (int j = 0; j < 4; ++j)
        crow[j * 16] = (float)acc[i][j][r] * (sxm * scl[j]) + bs[j];
    }
  }
}

extern "C" void kernel_launch(void* const* d_in, const int* in_sizes, int n_in,
                              void* d_out, int out_size, void* d_ws, size_t ws_size,
                              hipStream_t stream) {
  (void)in_sizes; (void)n_in; (void)out_size; (void)ws_size;
  const float* x = (const float*)d_in[0];     // [8192, 4096] fp32
  const float* w = (const float*)d_in[1];     // [4096, 4096] fp32
  const float* bias = (const float*)d_in[2];  // [4096] fp32
  float* out = (float*)d_out;                 // [8192, 4096] fp32

  char* ws = (char*)d_ws;
  char* qx = ws;                                           // 32 MB int8
  char* qw = ws + (size_t)33554432;                        // 16 MB int8
  float* sx = (float*)(ws + (size_t)50331648);             // 32 KB
  float* scale = (float*)(ws + (size_t)50331648 + 65536);  // 16 KB

  quantize_all<<<NDIM + MDIM, 256, 0, stream>>>(w, x, (unsigned*)qw,
                                                (unsigned*)qx, scale, sx);
  dim3 grid(NDIM / 128, MDIM / 128);  // (32, 64)
  gemm_i8<<<grid, 256, 0, stream>>>(qx, qw, sx, scale, bias, out);
}